// Round 2
// baseline (157.286 us; speedup 1.0000x reference)
//
#include <hip/hip_runtime.h>
#include <float.h>

// Problem constants (from reference setup_inputs)
#define B_SZ 2
#define N_SZ 16384
#define M_SZ 16384
#define E_SZ 49152

#define TPB 256
#define RPT 4                       // rows per thread
#define ROWS_PER_BLOCK (TPB * RPT)  // 1024
#define CHUNK 512                   // target points per block (LDS tile)

#define MIN_SLOTS (B_SZ * N_SZ + B_SZ * M_SZ)   // 65536 uints
#define NSUMS 6

// ---- sortable-uint mapping for float atomicMin (handles negatives) ----
__device__ inline unsigned fmapu(float f) {
    unsigned u = __float_as_uint(f);
    return ((int)u < 0) ? ~u : (u ^ 0x80000000u);
}
__device__ inline float funmapu(unsigned v) {
    unsigned b = ((int)v < 0) ? (v ^ 0x80000000u) : ~v;
    return __uint_as_float(b);
}

// ---- init workspace: minA/minB = 0xFFFFFFFF, sums = 0.0 ----
__global__ __launch_bounds__(TPB) void init_ws(unsigned* __restrict__ mins,
                                               double* __restrict__ sums) {
    int i = blockIdx.x * TPB + threadIdx.x;
    if (i < MIN_SLOTS) mins[i] = 0xFFFFFFFFu;
    if (i < NSUMS) sums[i] = 0.0;
}

// ---- chamfer pass: for each row of P, min over T of (0.5*|t|^2 - p.t) ----
// minOut[row] holds mapped-uint of phi = min_m(0.5*t2 - dot);  d2 = p2 + 2*phi
__global__ __launch_bounds__(TPB) void chamfer_pass(
    const float* __restrict__ P,   // (B, nRows, 3)
    const float* __restrict__ T,   // (B, mSearch, 3)
    unsigned* __restrict__ minOut, // (B*nRows), pre-init to 0xFFFFFFFF
    int nRows, int mSearch)
{
    __shared__ float4 sT[CHUNK];
    const int rowStart = blockIdx.x * ROWS_PER_BLOCK;   // global row (b*nRows+n)
    const int b = rowStart / nRows;                     // blocks never straddle batches
    const int mBase = blockIdx.y * CHUNK;

    // stage target chunk into LDS as {x, y, z, 0.5*|t|^2}
    const float* tb = T + ((size_t)b * mSearch + mBase) * 3;
    for (int i = threadIdx.x; i < CHUNK; i += TPB) {
        float x = tb[3 * i], y = tb[3 * i + 1], z = tb[3 * i + 2];
        sT[i] = make_float4(x, y, z, 0.5f * (x * x + y * y + z * z));
    }
    __syncthreads();

    float npx[RPT], npy[RPT], npz[RPT], acc[RPT];
    int rows[RPT];
    #pragma unroll
    for (int k = 0; k < RPT; k++) {
        int r = rowStart + threadIdx.x + k * TPB;
        rows[k] = r;
        const float* p = P + (size_t)r * 3;
        npx[k] = -p[0]; npy[k] = -p[1]; npz[k] = -p[2];
        acc[k] = FLT_MAX;
    }

    #pragma unroll 4
    for (int m = 0; m < CHUNK; m++) {
        float4 t = sT[m];  // uniform address -> LDS broadcast, conflict-free
        #pragma unroll
        for (int k = 0; k < RPT; k++) {
            acc[k] = fminf(acc[k],
                fmaf(npx[k], t.x, fmaf(npy[k], t.y, fmaf(npz[k], t.z, t.w))));
        }
    }

    #pragma unroll
    for (int k = 0; k < RPT; k++)
        atomicMin(&minOut[rows[k]], fmapu(acc[k]));
}

// ---- finalize: dist = sqrt(max(0, p2 + 2*phi)); sum into sums[0]/sums[1] ----
__global__ __launch_bounds__(TPB) void finalize_chamfer(
    const float* __restrict__ pred, const float* __restrict__ tgt,
    const unsigned* __restrict__ minA, const unsigned* __restrict__ minB,
    double* __restrict__ sums)
{
    const int rowsA = B_SZ * N_SZ;  // multiple of TPB -> block-uniform branch
    int idx = blockIdx.x * TPB + threadIdx.x;
    bool isA = idx < rowsA;
    int i = isA ? idx : idx - rowsA;
    const float* src = isA ? pred : tgt;
    const unsigned* mn = isA ? minA : minB;
    float x = src[3 * (size_t)i], y = src[3 * (size_t)i + 1], z = src[3 * (size_t)i + 2];
    float p2 = x * x + y * y + z * z;
    float phi = funmapu(mn[i]);
    float d = sqrtf(fmaxf(0.f, fmaf(2.f, phi, p2)));

    // block reduction
    __shared__ float warpSums[TPB / 64];
    for (int o = 32; o > 0; o >>= 1) d += __shfl_down(d, o, 64);
    int wave = threadIdx.x >> 6, lane = threadIdx.x & 63;
    if (lane == 0) warpSums[wave] = d;
    __syncthreads();
    if (threadIdx.x == 0) {
        float total = 0.f;
        #pragma unroll
        for (int w = 0; w < TPB / 64; w++) total += warpSums[w];
        atomicAdd(&sums[isA ? 0 : 1], (double)total);
    }
}

// ---- edge loss: per-b sum and sum of squares of edge lengths ----
// NOTE: harness passes integer inputs as int32 (not the reference's int64)
__global__ __launch_bounds__(TPB) void edge_kernel(
    const float* __restrict__ pred, const int* __restrict__ edges,
    double* __restrict__ sums /* sums[2+2b]=sum_b, sums[3+2b]=sumsq_b */)
{
    const int blocksPerB = E_SZ / TPB;  // 192, exact
    int b = blockIdx.x / blocksPerB;
    int e = (blockIdx.x % blocksPerB) * TPB + threadIdx.x;
    const int2* ed = (const int2*)edges;
    int2 ee = ed[e];
    const float* p0 = pred + ((size_t)b * N_SZ + (size_t)ee.x) * 3;
    const float* p1 = pred + ((size_t)b * N_SZ + (size_t)ee.y) * 3;
    float dx = p0[0] - p1[0];
    float dy = p0[1] - p1[1];
    float dz = p0[2] - p1[2];
    float len = sqrtf(dx * dx + dy * dy + dz * dz);

    __shared__ float ws0[TPB / 64], ws1[TPB / 64];
    float s = len, q = len * len;
    for (int o = 32; o > 0; o >>= 1) {
        s += __shfl_down(s, o, 64);
        q += __shfl_down(q, o, 64);
    }
    int wave = threadIdx.x >> 6, lane = threadIdx.x & 63;
    if (lane == 0) { ws0[wave] = s; ws1[wave] = q; }
    __syncthreads();
    if (threadIdx.x == 0) {
        float ts = 0.f, tq = 0.f;
        #pragma unroll
        for (int w = 0; w < TPB / 64; w++) { ts += ws0[w]; tq += ws1[w]; }
        atomicAdd(&sums[2 + 2 * b], (double)ts);
        atomicAdd(&sums[3 + 2 * b], (double)tq);
    }
}

// ---- combine to the 3 outputs ----
__global__ void final_kernel(const double* __restrict__ sums, float* __restrict__ out) {
    double c = sums[0] / (double)(B_SZ * N_SZ) + sums[1] / (double)(B_SZ * M_SZ);
    double e = 0.0;
    #pragma unroll
    for (int b = 0; b < B_SZ; b++) {
        double s = sums[2 + 2 * b], q = sums[3 + 2 * b];
        e += (q - s * s / (double)E_SZ) / (double)(E_SZ - 1);
    }
    e *= (1.0 / B_SZ);
    double tot = 1.0 * c + 0.1 * e;
    out[0] = (float)tot;
    out[1] = (float)c;
    out[2] = (float)e;
}

extern "C" void kernel_launch(void* const* d_in, const int* in_sizes, int n_in,
                              void* d_out, int out_size, void* d_ws, size_t ws_size,
                              hipStream_t stream) {
    const float* pred = (const float*)d_in[0];       // (B, N, 3) fp32
    const float* tgt  = (const float*)d_in[1];       // (B, M, 3) fp32
    const int* edges  = (const int*)d_in[2];         // (E, 2) int32 (harness-converted)
    float* out = (float*)d_out;

    // workspace layout: [minA (B*N u32)] [minB (B*M u32)] [sums (6 f64)]
    unsigned* minA = (unsigned*)d_ws;
    unsigned* minB = minA + (size_t)B_SZ * N_SZ;
    double* sums = (double*)((char*)d_ws + (size_t)MIN_SLOTS * sizeof(unsigned));

    // init workspace (kernel, not memset — graph-capture-safe)
    init_ws<<<dim3((MIN_SLOTS + TPB - 1) / TPB), TPB, 0, stream>>>(minA, sums);

    // chamfer passes (row-min over the other set), both directions
    dim3 gridA((B_SZ * N_SZ) / ROWS_PER_BLOCK, M_SZ / CHUNK); // 32 x 32
    chamfer_pass<<<gridA, TPB, 0, stream>>>(pred, tgt, minA, N_SZ, M_SZ);
    dim3 gridB((B_SZ * M_SZ) / ROWS_PER_BLOCK, N_SZ / CHUNK);
    chamfer_pass<<<gridB, TPB, 0, stream>>>(tgt, pred, minB, M_SZ, N_SZ);

    // edge loss (independent)
    edge_kernel<<<dim3(B_SZ * (E_SZ / TPB)), TPB, 0, stream>>>(pred, edges, sums);

    // reduce chamfer mins to sums
    finalize_chamfer<<<dim3((B_SZ * N_SZ + B_SZ * M_SZ) / TPB), TPB, 0, stream>>>(
        pred, tgt, minA, minB, sums);

    // combine
    final_kernel<<<dim3(1), dim3(1), 0, stream>>>(sums, out);
}